// Round 17
// baseline (74.324 us; speedup 1.0000x reference)
//
#include <hip/hip_runtime.h>
#include <math.h>

#define BB 4
#define TT 4096
#define CC 1024
#define HH 64
#define MM (BB*TT)

typedef __attribute__((ext_vector_type(8))) short  short8;
typedef __attribute__((ext_vector_type(4))) short  short4v;
typedef __attribute__((ext_vector_type(4))) float  f32x4;

static __device__ __forceinline__ unsigned short f2bf(float f) {
    union { float f; unsigned u; } v; v.f = f;
    unsigned r = v.u + 0x7FFF + ((v.u >> 16) & 1);
    return (unsigned short)(r >> 16);
}

// 8x fp32 -> 8x bf16 (RNE) via v_cvt_pk_bf16_f32
static __device__ __forceinline__ short8 cvt8(float4 lo, float4 hi) {
    unsigned u0, u1, u2, u3;
    asm("v_cvt_pk_bf16_f32 %0, %1, %2" : "=v"(u0) : "v"(lo.x), "v"(lo.y));
    asm("v_cvt_pk_bf16_f32 %0, %1, %2" : "=v"(u1) : "v"(lo.z), "v"(lo.w));
    asm("v_cvt_pk_bf16_f32 %0, %1, %2" : "=v"(u2) : "v"(hi.x), "v"(hi.y));
    asm("v_cvt_pk_bf16_f32 %0, %1, %2" : "=v"(u3) : "v"(hi.z), "v"(hi.w));
    union { unsigned u[4]; short8 s; } r;
    r.u[0] = u0; r.u[1] = u1; r.u[2] = u2; r.u[3] = u3;
    return r.s;
}

// ---------------- Kernel 0: W -> W^T bf16 (tiny, unchanged) ----------------
__global__ __launch_bounds__(256) void convw_kernel(
        const float* __restrict__ Wq, const float* __restrict__ Wk,
        const float* __restrict__ Wv, unsigned short* __restrict__ wtb) {
    __shared__ unsigned short sW[64][66];
    const int m    = blockIdx.x >> 4;
    const int cblk = blockIdx.x & 15;
    const float* W = (m == 0) ? Wq : (m == 1) ? Wk : Wv;
    const int lane = threadIdx.x & 63;
    const int w    = threadIdx.x >> 6;
    #pragma unroll
    for (int rep = 0; rep < 16; ++rep) {
        const int cl = w * 16 + rep;
        sW[cl][lane] = f2bf(W[(size_t)(cblk * 64 + cl) * HH + lane]);
    }
    __syncthreads();
    #pragma unroll
    for (int rep = 0; rep < 16; ++rep) {
        const int h2 = w * 16 + rep;
        wtb[(size_t)(m * 64 + h2) * CC + cblk * 64 + lane] = sW[lane][h2];
    }
}

// ---------------- Kernel 1: W-resident-LDS, zero-barrier MFMA projection ---
// grid (128, 3): bx = 128-row tile, by = m (q/k/v). 256 thr = 4 waves,
// wave w owns rows [w*32, w*32+32) x all 64 cols of matrix m.
// Prologue: W_m^T (64x1024 bf16 = 128 KB) -> LDS once (XOR-swizzled rows).
// K-loop: NO barriers. A: per-lane global fp32 (depth-2 reg ring, cvt at
// use); B: ds_read_b128 from resident W. Waves slip freely; x re-read 3x
// rides L3 (x is 64 MB, L3-resident).
__global__ __launch_bounds__(256, 1) void gemm_kernel(
        const float* __restrict__ x,
        const unsigned short* __restrict__ wtb,
        unsigned short* __restrict__ qb,
        unsigned short* __restrict__ kb,
        unsigned short* __restrict__ vt) {
    __shared__ char smem[64 * 2048];   // 128 KB: W^T[64][128 slots of 16B]

    const int tid  = threadIdx.x;
    const int lane = tid & 63;
    const int w    = tid >> 6;
    const int l15  = lane & 15;
    const int lg   = lane >> 4;
    const int row0 = blockIdx.x * 128;
    const int m    = blockIdx.y;
    const unsigned short* Wm = wtb + (size_t)m * 64 * CC;

    // ---- prologue: stage W_m^T into LDS, slot p holds source slot p^(n&7) ----
    {
        const int n  = tid & 63;          // W row (output col h)
        const int jb = tid >> 6;          // slot block 0..3
        const unsigned short* wrow = Wm + (size_t)n * CC;
        char* ldrow = smem + n * 2048;
        #pragma unroll
        for (int j = 0; j < 32; ++j) {
            const int p = jb * 32 + j;
            short8 v = *(const short8*)(wrow + (size_t)((p ^ (n & 7)) * 8));
            *(short8*)(ldrow + p * 16) = v;
        }
    }
    __syncthreads();   // the only pre-epilogue barrier

    f32x4 acc[2][4];   // [mf][nf]
    #pragma unroll
    for (int i = 0; i < 2; ++i)
        #pragma unroll
        for (int j = 0; j < 4; ++j)
            acc[i][j] = (f32x4){0.f, 0.f, 0.f, 0.f};

    const int wrowbase = row0 + w * 32;
    const float* xr0 = x + (size_t)(wrowbase + l15) * CC + lg * 8;
    const float* xr1 = x + (size_t)(wrowbase + 16 + l15) * CC + lg * 8;

    float4 aring[3][8];   // depth-2 ring: [slot][mf*4 + kh*2 + half]

#define LOAD_A(s_, sl_) { \
    const int kc_ = (s_) * 64; \
    aring[sl_][0] = *(const float4*)(xr0 + kc_);        \
    aring[sl_][1] = *(const float4*)(xr0 + kc_ + 4);    \
    aring[sl_][2] = *(const float4*)(xr0 + kc_ + 32);   \
    aring[sl_][3] = *(const float4*)(xr0 + kc_ + 36);   \
    aring[sl_][4] = *(const float4*)(xr1 + kc_);        \
    aring[sl_][5] = *(const float4*)(xr1 + kc_ + 4);    \
    aring[sl_][6] = *(const float4*)(xr1 + kc_ + 32);   \
    aring[sl_][7] = *(const float4*)(xr1 + kc_ + 36);   }

    LOAD_A(0, 0); LOAD_A(1, 1);

    #pragma unroll
    for (int t = 0; t < 16; ++t) {
        if (t < 14) LOAD_A(t + 2, (t + 2) % 3);

        short8 af[2][2];
        af[0][0] = cvt8(aring[t % 3][0], aring[t % 3][1]);
        af[0][1] = cvt8(aring[t % 3][2], aring[t % 3][3]);
        af[1][0] = cvt8(aring[t % 3][4], aring[t % 3][5]);
        af[1][1] = cvt8(aring[t % 3][6], aring[t % 3][7]);

        short8 bf[4][2];
        #pragma unroll
        for (int nf = 0; nf < 4; ++nf)
            #pragma unroll
            for (int kh = 0; kh < 2; ++kh) {
                const int n    = nf * 16 + l15;
                const int koct = t * 8 + kh * 4 + lg;
                bf[nf][kh] = *(const short8*)(
                    smem + n * 2048 + ((koct ^ (n & 7)) * 16));
            }
        #pragma unroll
        for (int kh = 0; kh < 2; ++kh)
            #pragma unroll
            for (int nf = 0; nf < 4; ++nf)
                #pragma unroll
                for (int mf = 0; mf < 2; ++mf)
                    acc[mf][nf] = __builtin_amdgcn_mfma_f32_16x16x32_bf16(
                        af[mf][kh], bf[nf][kh], acc[mf][nf], 0, 0, 0);
    }
#undef LOAD_A

    // ---- epilogue ----
    if (m < 2) {
        unsigned short* dst = (m == 0) ? qb : kb;
        #pragma unroll
        for (int nf = 0; nf < 4; ++nf) {
            const int h = nf * 16 + l15;
            #pragma unroll
            for (int mf = 0; mf < 2; ++mf) {
                const int rowb = wrowbase + mf * 16 + lg * 4;
                #pragma unroll
                for (int r = 0; r < 4; ++r)
                    dst[(size_t)(rowb + r) * HH + h] = f2bf(acc[mf][nf][r]);
            }
        }
    } else {
        // v: transpose via reused W LDS (all waves past the K-loop first)
        __syncthreads();
        float* stage = (float*)smem;      // [64][132] floats = 33 KB
        #pragma unroll
        for (int nf = 0; nf < 4; ++nf) {
            const int h = nf * 16 + l15;
            #pragma unroll
            for (int mf = 0; mf < 2; ++mf) {
                const int lr = w * 32 + mf * 16 + lg * 4;
                #pragma unroll
                for (int r = 0; r < 4; ++r)
                    stage[h * 132 + lr + r] = acc[mf][nf][r];
            }
        }
        __syncthreads();
        const int h   = tid >> 2;
        const int seg = tid & 3;
        const int b   = row0 >> 12;
        unsigned short* vrow = vt + ((size_t)(b * 64 + h)) * TT
                                  + (row0 & (TT - 1)) + seg * 32;
        #pragma unroll
        for (int j = 0; j < 8; ++j) {
            short4v o;
            #pragma unroll
            for (int e = 0; e < 4; ++e)
                o[e] = (short)f2bf(stage[h * 132 + seg * 32 + j * 4 + e]);
            *reinterpret_cast<short4v*>(vrow + j * 4) = o;
        }
    }
}

// ---------------- Kernel 2: MFMA windowed causal attention (r4/r13) --------
__global__ __launch_bounds__(256) void attn_kernel(
        const unsigned short* __restrict__ qb,
        const unsigned short* __restrict__ kb,
        const unsigned short* __restrict__ vt,
        const float* __restrict__ decay,
        float* __restrict__ out) {
    __shared__ unsigned short P[4][16 * 168];

    const int lane = threadIdx.x & 63;
    const int w    = threadIdx.x >> 6;
    const int l15  = lane & 15;
    const int lg   = lane >> 4;
    const int qt   = blockIdx.x * 4 + w;
    const int gb   = qt >> 8;
    const int i0   = (qt & 255) << 4;

    const float dec = fabsf(decay[0]);
    const size_t bbase = (size_t)gb * TT;

    short8 af0, af1;
    {
        const unsigned short* qp = qb + (bbase + i0 + l15) * HH + lg * 8;
        af0 = *(const short8*)(qp);
        af1 = *(const short8*)(qp + 32);
    }

    float psum[4] = {0.f, 0.f, 0.f, 0.f};
    unsigned short* Pw = &P[w][0];

    if (i0 >= 144) {
        const int js = i0 - 144;
        const unsigned short* kp = kb + (bbase + js + l15) * HH + lg * 8;
        #pragma unroll
        for (int ts = 0; ts < 10; ++ts) {
            short8 b0 = *(const short8*)(kp + (size_t)ts * 16 * HH);
            short8 b1 = *(const short8*)(kp + (size_t)ts * 16 * HH + 32);
            f32x4 s = (f32x4){0.f, 0.f, 0.f, 0.f};
            s = __builtin_amdgcn_mfma_f32_16x16x32_bf16(af0, b0, s, 0, 0, 0);
            s = __builtin_amdgcn_mfma_f32_16x16x32_bf16(af1, b1, s, 0, 0, 0);
            const int d0 = 144 + lg * 4 - ts * 16 - l15;
            #pragma unroll
            for (int r = 0; r < 4; ++r) {
                const int d = d0 + r;
                float sv = s[r] * 0.125f - dec * (float)d - 12.0f;
                float p  = (ts == 9 && d < 0) ? 0.0f : __expf(sv);
                psum[r] += p;
                Pw[(lg * 4 + r) * 168 + ts * 16 + l15] = f2bf(p);
            }
        }
        #pragma unroll
        for (int off = 1; off < 16; off <<= 1)
            #pragma unroll
            for (int r = 0; r < 4; ++r)
                psum[r] += __shfl_xor(psum[r], off, 64);

        asm volatile("s_waitcnt lgkmcnt(0)" ::: "memory");
        __builtin_amdgcn_sched_barrier(0);

        f32x4 oacc[4];
        #pragma unroll
        for (int ht = 0; ht < 4; ++ht) oacc[ht] = (f32x4){0.f, 0.f, 0.f, 0.f};
        const unsigned short* vp = vt + ((size_t)(gb * 64) + l15) * TT + js + lg * 8;

        __builtin_amdgcn_s_setprio(1);
        #pragma unroll
        for (int kt = 0; kt < 5; ++kt) {
            short8 pa = *(const short8*)((const char*)Pw + l15 * 336 + kt * 64 + lg * 16);
            #pragma unroll
            for (int ht = 0; ht < 4; ++ht) {
                short8 bv = *(const short8*)(vp + (size_t)ht * 16 * TT + kt * 32);
                oacc[ht] = __builtin_amdgcn_mfma_f32_16x16x32_bf16(pa, bv, oacc[ht], 0, 0, 0);
            }
        }
        __builtin_amdgcn_s_setprio(0);

        float inv[4];
        #pragma unroll
        for (int r = 0; r < 4; ++r) inv[r] = 1.0f / psum[r];
        float* op = out + (bbase + i0 + lg * 4) * HH + l15;
        #pragma unroll
        for (int ht = 0; ht < 4; ++ht)
            #pragma unroll
            for (int r = 0; r < 4; ++r)
                op[(size_t)r * HH + ht * 16] = oacc[ht][r] * inv[r];
    } else {
        const int NS = (i0 >> 4) + 1;
        const int NK = (NS + 1) >> 1;
        const int dbase = i0 + lg * 4 - l15;
        const unsigned short* kp = kb + (bbase + l15) * HH + lg * 8;

        for (int ts = 0; ts < NS; ++ts) {
            short8 b0 = *(const short8*)(kp);
            short8 b1 = *(const short8*)(kp + 32);
            kp += 16 * HH;
            f32x4 s = (f32x4){0.f, 0.f, 0.f, 0.f};
            s = __builtin_amdgcn_mfma_f32_16x16x32_bf16(af0, b0, s, 0, 0, 0);
            s = __builtin_amdgcn_mfma_f32_16x16x32_bf16(af1, b1, s, 0, 0, 0);
            const int d0 = dbase - ts * 16;
            #pragma unroll
            for (int r = 0; r < 4; ++r) {
                const int d = d0 + r;
                float sv = s[r] * 0.125f - dec * (float)d - 12.0f;
                float p  = (d < 0) ? 0.0f : __expf(sv);
                psum[r] += p;
                Pw[(lg * 4 + r) * 168 + ts * 16 + l15] = f2bf(p);
            }
        }
        if (NS & 1) {
            #pragma unroll
            for (int r = 0; r < 4; ++r)
                Pw[(lg * 4 + r) * 168 + NS * 16 + l15] = 0;
        }
        #pragma unroll
        for (int off = 1; off < 16; off <<= 1)
            #pragma unroll
            for (int r = 0; r < 4; ++r)
                psum[r] += __shfl_xor(psum[r], off, 64);

        asm volatile("s_waitcnt lgkmcnt(0)" ::: "memory");
        __builtin_amdgcn_sched_barrier(0);

        f32x4 oacc[4];
        #pragma unroll
        for (int ht = 0; ht < 4; ++ht) oacc[ht] = (f32x4){0.f, 0.f, 0.f, 0.f};
        const unsigned short* vp = vt + ((size_t)(gb * 64) + l15) * TT + lg * 8;

        for (int kt = 0; kt < NK; ++kt) {
            short8 pa = *(const short8*)((const char*)Pw + l15 * 336 + kt * 64 + lg * 16);
            #pragma unroll
            for (int ht = 0; ht < 4; ++ht) {
                short8 bv = *(const short8*)(vp + (size_t)ht * 16 * TT + kt * 32);
                oacc[ht] = __builtin_amdgcn_mfma_f32_16x16x32_bf16(pa, bv, oacc[ht], 0, 0, 0);
            }
        }

        float inv[4];
        #pragma unroll
        for (int r = 0; r < 4; ++r) inv[r] = 1.0f / psum[r];
        float* op = out + (bbase + i0 + lg * 4) * HH + l15;
        #pragma unroll
        for (int ht = 0; ht < 4; ++ht)
            #pragma unroll
            for (int r = 0; r < 4; ++r)
                op[(size_t)r * HH + ht * 16] = oacc[ht][r] * inv[r];
    }
}

extern "C" void kernel_launch(void* const* d_in, const int* in_sizes, int n_in,
                              void* d_out, int out_size, void* d_ws, size_t ws_size,
                              hipStream_t stream) {
    const float* x     = (const float*)d_in[0];
    const float* Wq    = (const float*)d_in[1];
    const float* Wk    = (const float*)d_in[2];
    const float* Wv    = (const float*)d_in[3];
    const float* decay = (const float*)d_in[4];
    float* out = (float*)d_out;

    unsigned short* qb  = (unsigned short*)d_ws;          // 2 MB
    unsigned short* kb  = qb + (size_t)MM * HH;           // 2 MB
    unsigned short* vt  = kb + (size_t)MM * HH;           // 2 MB (transposed)
    unsigned short* wtb = vt + (size_t)MM * HH;           // 384 KB

    convw_kernel<<<48, 256, 0, stream>>>(Wq, Wk, Wv, wtb);
    gemm_kernel<<<dim3(128, 3), 256, 0, stream>>>(x, wtb, qb, kb, vt);
    attn_kernel<<<MM / 64, 256, 0, stream>>>(qb, kb, vt, decay, out);
}

// Round 18
// 35.109 us; speedup vs baseline: 2.1169x; 2.1169x over previous
//
#include <hip/hip_runtime.h>
#include <math.h>

#define BB 4
#define TT 4096
#define CC 1024
#define HH 64
#define MM (BB*TT)

typedef __attribute__((ext_vector_type(8))) short  short8;
typedef __attribute__((ext_vector_type(4))) short  short4v;
typedef __attribute__((ext_vector_type(4))) float  f32x4;

typedef const __attribute__((address_space(1))) unsigned int GU;
typedef __attribute__((address_space(3))) unsigned int LU;

static __device__ __forceinline__ unsigned short f2bf(float f) {
    union { float f; unsigned u; } v; v.f = f;
    unsigned r = v.u + 0x7FFF + ((v.u >> 16) & 1);
    return (unsigned short)(r >> 16);
}

// 4x fp32 -> 4x bf16 (RNE) via v_cvt_pk_bf16_f32
static __device__ __forceinline__ short4v cvt4(float4 a) {
    unsigned u0, u1;
    asm("v_cvt_pk_bf16_f32 %0, %1, %2" : "=v"(u0) : "v"(a.x), "v"(a.y));
    asm("v_cvt_pk_bf16_f32 %0, %1, %2" : "=v"(u1) : "v"(a.z), "v"(a.w));
    union { unsigned u[2]; short4v s; } r;
    r.u[0] = u0; r.u[1] = u1;
    return r.s;
}

// ---------------- Kernel 0: W -> W^T bf16 (tiny) ----------------
__global__ __launch_bounds__(256) void convw_kernel(
        const float* __restrict__ Wq, const float* __restrict__ Wk,
        const float* __restrict__ Wv, unsigned short* __restrict__ wtb) {
    __shared__ unsigned short sW[64][66];
    const int m    = blockIdx.x >> 4;
    const int cblk = blockIdx.x & 15;
    const float* W = (m == 0) ? Wq : (m == 1) ? Wk : Wv;
    const int lane = threadIdx.x & 63;
    const int w    = threadIdx.x >> 6;
    #pragma unroll
    for (int rep = 0; rep < 16; ++rep) {
        const int cl = w * 16 + rep;
        sW[cl][lane] = f2bf(W[(size_t)(cblk * 64 + cl) * HH + lane]);
    }
    __syncthreads();
    #pragma unroll
    for (int rep = 0; rep < 16; ++rep) {
        const int h2 = w * 16 + rep;
        wtb[(size_t)(m * 64 + h2) * CC + cblk * 64 + lane] = sW[lane][h2];
    }
}

// ---------------- Kernel 1: r13 gemm (measured best: 34.8 us total) --------
// BM=32, BN=192, BK=64, grid=512, 512 thr = 8 waves (2 rg x 4 cg of 48).
// B: 3x24KB LDS ring via global_load_lds, 2 steps ahead; wait vmcnt(8).
// A: fp32 global->reg (3-slot ring) -> cvt_pk -> single 4KB LDS buffer.
__global__ __launch_bounds__(512, 2) void gemm_kernel(
        const float* __restrict__ x,
        const unsigned short* __restrict__ wtb,
        unsigned short* __restrict__ qb,
        unsigned short* __restrict__ kb,
        unsigned short* __restrict__ vt) {
    __shared__ unsigned short As[32 * 64];       // 4 KB, single buffer
    __shared__ unsigned short Bs[3][192 * 64];   // 3 x 24 KB ring

    const int tid  = threadIdx.x;
    const int lane = tid & 63;
    const int w    = tid >> 6;
    const int l15  = lane & 15;
    const int lg   = lane >> 4;
    const int row0 = blockIdx.x * 32;
    const int rg   = (w >> 2) * 16;     // row group: 0 or 16
    const int wc   = (w & 3) * 48;      // col group base

    f32x4 acc[3];
    #pragma unroll
    for (int j = 0; j < 3; ++j) acc[j] = (f32x4){0.f, 0.f, 0.f, 0.f};

    const int ar   = tid >> 4;            // 0..31
    const int akq  = (tid & 15) >> 1;     // 0..7
    const int half = tid & 1;
    const float* xrow = x + (size_t)(row0 + ar) * CC + akq * 8 + half * 4;
    char* adst = (char*)As + ar * 128 + ((akq ^ (ar & 7)) * 16) + half * 8;

    float4 araw[3];

#define STAGE_B(s_, bufi_) { \
    const int kc_ = (s_) * 64; \
    _Pragma("unroll") \
    for (int it = 0; it < 3; ++it) { \
        const int lidx = it * 8192 + tid * 16; \
        const int r_  = lidx >> 7; \
        const int cb_ = (((lidx & 127) >> 4) ^ (r_ & 7)); \
        __builtin_amdgcn_global_load_lds( \
            (GU*)(wtb + (size_t)r_ * CC + kc_ + cb_ * 8), \
            (LU*)((char*)Bs[bufi_] + it * 8192 + w * 1024), 16, 0, 0); \
    } }
#define LOAD_A(s_, sl_) { \
    araw[sl_] = *(const float4*)(xrow + (s_) * 64); }

    // ---- prologue: 2 steps in flight (8 VMEM instrs/thread) ----
    STAGE_B(0, 0); LOAD_A(0, 0);
    STAGE_B(1, 1); LOAD_A(1, 1);

    const int swz = (l15 & 7) << 4;

    #pragma unroll
    for (int t = 0; t < 16; ++t) {
        if (t < 14) { STAGE_B(t + 2, (t + 2) % 3); LOAD_A(t + 2, (t + 2) % 3); }
        __builtin_amdgcn_sched_barrier(0);
        if (t < 14)       { asm volatile("s_waitcnt vmcnt(8)" ::: "memory"); }
        else if (t == 14) { asm volatile("s_waitcnt vmcnt(4)" ::: "memory"); }
        else              { asm volatile("s_waitcnt vmcnt(0)" ::: "memory"); }

        // cvt + ds_write A(t)
        short4v av = cvt4(araw[t % 3]);
        *reinterpret_cast<short4v*>(adst) = av;
        asm volatile("s_waitcnt lgkmcnt(0)" ::: "memory");
        __builtin_amdgcn_sched_barrier(0);
        __builtin_amdgcn_s_barrier();        // #1: B(t) + A(t) visible

        const char* Asc = (const char*)As;
        const char* Bsc = (const char*)Bs[t % 3];
        short8 af[2];
        #pragma unroll
        for (int kh = 0; kh < 2; ++kh)
            af[kh] = *(const short8*)(Asc + (rg + l15) * 128 + ((kh * 64 + lg * 16) ^ swz));
        short8 bf[3][2];
        #pragma unroll
        for (int nf = 0; nf < 3; ++nf)
            #pragma unroll
            for (int kh = 0; kh < 2; ++kh) {
                const int n = wc + nf * 16 + l15;
                bf[nf][kh] = *(const short8*)(Bsc + n * 128 + ((kh * 64 + lg * 16) ^ swz));
            }
        __builtin_amdgcn_s_setprio(1);
        #pragma unroll
        for (int kh = 0; kh < 2; ++kh)
            #pragma unroll
            for (int nf = 0; nf < 3; ++nf)
                acc[nf] = __builtin_amdgcn_mfma_f32_16x16x32_bf16(
                    af[kh], bf[nf][kh], acc[nf], 0, 0, 0);
        __builtin_amdgcn_s_setprio(0);

        __builtin_amdgcn_s_barrier();        // #2: release Bs[t%3], As
        __builtin_amdgcn_sched_barrier(0);
    }
#undef STAGE_B
#undef LOAD_A

    // ---- epilogue: q,k row-major bf16; v transposed vt[b][h][t] ----
    const int b = row0 >> 12;
    #pragma unroll
    for (int nf = 0; nf < 3; ++nf) {
        const int ng = wc + nf * 16 + l15;
        const int m  = ng >> 6, h = ng & 63;
        const int rowbase = row0 + rg + lg * 4;
        if (m == 2) {
            short4v pk;
            pk[0] = (short)f2bf(acc[nf][0]);
            pk[1] = (short)f2bf(acc[nf][1]);
            pk[2] = (short)f2bf(acc[nf][2]);
            pk[3] = (short)f2bf(acc[nf][3]);
            *reinterpret_cast<short4v*>(
                &vt[((size_t)(b * 64 + h)) * TT + (rowbase & (TT - 1))]) = pk;
        } else {
            unsigned short* dst = (m == 0) ? qb : kb;
            #pragma unroll
            for (int r = 0; r < 4; ++r)
                dst[(size_t)(rowbase + r) * HH + h] = f2bf(acc[nf][r]);
        }
    }
}

// ---------------- Kernel 2: MFMA windowed causal attention (r4/r13) --------
// One wave per 16-row q-tile. Fixed-max softmax: p = exp(s - 12).
__global__ __launch_bounds__(256) void attn_kernel(
        const unsigned short* __restrict__ qb,
        const unsigned short* __restrict__ kb,
        const unsigned short* __restrict__ vt,
        const float* __restrict__ decay,
        float* __restrict__ out) {
    __shared__ unsigned short P[4][16 * 168];

    const int lane = threadIdx.x & 63;
    const int w    = threadIdx.x >> 6;
    const int l15  = lane & 15;
    const int lg   = lane >> 4;
    const int qt   = blockIdx.x * 4 + w;
    const int gb   = qt >> 8;
    const int i0   = (qt & 255) << 4;

    const float dec = fabsf(decay[0]);
    const size_t bbase = (size_t)gb * TT;

    short8 af0, af1;
    {
        const unsigned short* qp = qb + (bbase + i0 + l15) * HH + lg * 8;
        af0 = *(const short8*)(qp);
        af1 = *(const short8*)(qp + 32);
    }

    float psum[4] = {0.f, 0.f, 0.f, 0.f};
    unsigned short* Pw = &P[w][0];

    if (i0 >= 144) {
        const int js = i0 - 144;
        const unsigned short* kp = kb + (bbase + js + l15) * HH + lg * 8;
        #pragma unroll
        for (int ts = 0; ts < 10; ++ts) {
            short8 b0 = *(const short8*)(kp + (size_t)ts * 16 * HH);
            short8 b1 = *(const short8*)(kp + (size_t)ts * 16 * HH + 32);
            f32x4 s = (f32x4){0.f, 0.f, 0.f, 0.f};
            s = __builtin_amdgcn_mfma_f32_16x16x32_bf16(af0, b0, s, 0, 0, 0);
            s = __builtin_amdgcn_mfma_f32_16x16x32_bf16(af1, b1, s, 0, 0, 0);
            const int d0 = 144 + lg * 4 - ts * 16 - l15;
            #pragma unroll
            for (int r = 0; r < 4; ++r) {
                const int d = d0 + r;
                float sv = s[r] * 0.125f - dec * (float)d - 12.0f;
                float p  = (ts == 9 && d < 0) ? 0.0f : __expf(sv);
                psum[r] += p;
                Pw[(lg * 4 + r) * 168 + ts * 16 + l15] = f2bf(p);
            }
        }
        #pragma unroll
        for (int off = 1; off < 16; off <<= 1)
            #pragma unroll
            for (int r = 0; r < 4; ++r)
                psum[r] += __shfl_xor(psum[r], off, 64);

        asm volatile("s_waitcnt lgkmcnt(0)" ::: "memory");
        __builtin_amdgcn_sched_barrier(0);

        f32x4 oacc[4];
        #pragma unroll
        for (int ht = 0; ht < 4; ++ht) oacc[ht] = (f32x4){0.f, 0.f, 0.f, 0.f};
        const unsigned short* vp = vt + ((size_t)(gb * 64) + l15) * TT + js + lg * 8;

        __builtin_amdgcn_s_setprio(1);
        #pragma unroll
        for (int kt = 0; kt < 5; ++kt) {
            short8 pa = *(const short8*)((const char*)Pw + l15 * 336 + kt * 64 + lg * 16);
            #pragma unroll
            for (int ht = 0; ht < 4; ++ht) {
                short8 bv = *(const short8*)(vp + (size_t)ht * 16 * TT + kt * 32);
                oacc[ht] = __builtin_amdgcn_mfma_f32_16x16x32_bf16(pa, bv, oacc[ht], 0, 0, 0);
            }
        }
        __builtin_amdgcn_s_setprio(0);

        float inv[4];
        #pragma unroll
        for (int r = 0; r < 4; ++r) inv[r] = 1.0f / psum[r];
        float* op = out + (bbase + i0 + lg * 4) * HH + l15;
        #pragma unroll
        for (int ht = 0; ht < 4; ++ht)
            #pragma unroll
            for (int r = 0; r < 4; ++r)
                op[(size_t)r * HH + ht * 16] = oacc[ht][r] * inv[r];
    } else {
        const int NS = (i0 >> 4) + 1;
        const int NK = (NS + 1) >> 1;
        const int dbase = i0 + lg * 4 - l15;
        const unsigned short* kp = kb + (bbase + l15) * HH + lg * 8;

        for (int ts = 0; ts < NS; ++ts) {
            short8 b0 = *(const short8*)(kp);
            short8 b1 = *(const short8*)(kp + 32);
            kp += 16 * HH;
            f32x4 s = (f32x4){0.f, 0.f, 0.f, 0.f};
            s = __builtin_amdgcn_mfma_f32_16x16x32_bf16(af0, b0, s, 0, 0, 0);
            s = __builtin_amdgcn_mfma_f32_16x16x32_bf16(af1, b1, s, 0, 0, 0);
            const int d0 = dbase - ts * 16;
            #pragma unroll
            for (int r = 0; r < 4; ++r) {
                const int d = d0 + r;
                float sv = s[r] * 0.125f - dec * (float)d - 12.0f;
                float p  = (d < 0) ? 0.0f : __expf(sv);
                psum[r] += p;
                Pw[(lg * 4 + r) * 168 + ts * 16 + l15] = f2bf(p);
            }
        }
        if (NS & 1) {
            #pragma unroll
            for (int r = 0; r < 4; ++r)
                Pw[(lg * 4 + r) * 168 + NS * 16 + l15] = 0;
        }
        #pragma unroll
        for (int off = 1; off < 16; off <<= 1)
            #pragma unroll
            for (int r = 0; r < 4; ++r)
                psum[r] += __shfl_xor(psum[r], off, 64);

        asm volatile("s_waitcnt lgkmcnt(0)" ::: "memory");
        __builtin_amdgcn_sched_barrier(0);

        f32x4 oacc[4];
        #pragma unroll
        for (int ht = 0; ht < 4; ++ht) oacc[ht] = (f32x4){0.f, 0.f, 0.f, 0.f};
        const unsigned short* vp = vt + ((size_t)(gb * 64) + l15) * TT + lg * 8;

        for (int kt = 0; kt < NK; ++kt) {
            short8 pa = *(const short8*)((const char*)Pw + l15 * 336 + kt * 64 + lg * 16);
            #pragma unroll
            for (int ht = 0; ht < 4; ++ht) {
                short8 bv = *(const short8*)(vp + (size_t)ht * 16 * TT + kt * 32);
                oacc[ht] = __builtin_amdgcn_mfma_f32_16x16x32_bf16(pa, bv, oacc[ht], 0, 0, 0);
            }
        }

        float inv[4];
        #pragma unroll
        for (int r = 0; r < 4; ++r) inv[r] = 1.0f / psum[r];
        float* op = out + (bbase + i0 + lg * 4) * HH + l15;
        #pragma unroll
        for (int ht = 0; ht < 4; ++ht)
            #pragma unroll
            for (int r = 0; r < 4; ++r)
                op[(size_t)r * HH + ht * 16] = oacc[ht][r] * inv[r];
    }
}

extern "C" void kernel_launch(void* const* d_in, const int* in_sizes, int n_in,
                              void* d_out, int out_size, void* d_ws, size_t ws_size,
                              hipStream_t stream) {
    const float* x     = (const float*)d_in[0];
    const float* Wq    = (const float*)d_in[1];
    const float* Wk    = (const float*)d_in[2];
    const float* Wv    = (const float*)d_in[3];
    const float* decay = (const float*)d_in[4];
    float* out = (float*)d_out;

    unsigned short* qb  = (unsigned short*)d_ws;          // 2 MB
    unsigned short* kb  = qb + (size_t)MM * HH;           // 2 MB
    unsigned short* vt  = kb + (size_t)MM * HH;           // 2 MB (transposed)
    unsigned short* wtb = vt + (size_t)MM * HH;           // 384 KB

    convw_kernel<<<48, 256, 0, stream>>>(Wq, Wk, Wv, wtb);
    gemm_kernel<<<MM / 32, 512, 0, stream>>>(x, wtb, qb, kb, vt);
    attn_kernel<<<MM / 64, 256, 0, stream>>>(qb, kb, vt, decay, out);
}